// Round 10
// baseline (317.739 us; speedup 1.0000x reference)
//
#include <hip/hip_runtime.h>
#include <stdint.h>

#define N_NODES 6144
#define LOG2E 1.44269504088896f

typedef float f32x4 __attribute__((ext_vector_type(4)));
typedef short short8 __attribute__((ext_vector_type(8)));
typedef unsigned int uint32;
typedef unsigned long long uint64;

extern "C" __device__ float __ocml_native_exp2_f32(float);

// pack two floats -> two bf16 (round-half-up) in one u32: lo=a, hi=b
__device__ __forceinline__ unsigned int pack2bf(float a, float b) {
  unsigned int ua = __float_as_uint(a) + 0x8000u;
  unsigned int ub = __float_as_uint(b) + 0x8000u;
  return __builtin_amdgcn_perm(ub, ua, 0x07060302u);
}

// K0: bit-pack adjacency via wave ballot. Lane reads ONE int (coalesced
// 256B per wave instr), ballot packs 64 edges, one lane stores the u64.
// u64 word c of row = cols [64c, 64c+64), bit j (LE) = col 64c+j.
__global__ __launch_bounds__(256) void k0_pack(const int* __restrict__ adj,
                                               uint64* __restrict__ mask64) {
  int t = threadIdx.x;
  int wid = t >> 6, lane = t & 63;
  int row = blockIdx.x * 4 + wid;
  const int* ar = adj + (size_t)row * N_NODES + lane;
  uint64* mr = mask64 + (size_t)row * 96;
  #pragma unroll 8
  for (int c = 0; c < 96; ++c) {
    int v = ar[c << 6];
    uint64 b = __ballot(v != 0);
    if (lane == (c & 63)) mr[c] = b;
  }
}

// K1: h = x*W (fp32). hfT (bf16 [c][n]) coalesced via LDS transpose;
// s_src2/s_dst2 = (h . a_{src,dst}) * log2(e).
__global__ __launch_bounds__(256) void k1_feat(const float* __restrict__ x,
                                               const float* __restrict__ W,
                                               const float* __restrict__ a,
                                               unsigned short* __restrict__ hfT,
                                               float* __restrict__ s_src2,
                                               float* __restrict__ s_dst2) {
  __shared__ float xl[64][132];
  __shared__ float Wl[64][128];
  int t = threadIdx.x;
  int n0 = blockIdx.x * 64;
  for (int u = t; u < 2048; u += 256) {
    int row = u >> 5, c4 = (u & 31) << 2;
    *(float4*)&xl[row][c4] = *(const float4*)(x + (size_t)(n0 + row) * 128 + c4);
  }
  int cg = t & 31, c0 = cg << 2;
  int ng = t >> 5, nb = ng << 3;
  float acc[8][4] = {};
  for (int ic = 0; ic < 2; ++ic) {
    __syncthreads();
    for (int u = t; u < 2048; u += 256) {
      int ii = u >> 5, c4 = (u & 31) << 2;
      int hh = c4 >> 5, d0 = c4 & 31;
      *(float4*)&Wl[ii][c4] = *(const float4*)(W + hh * 4096 + (ic * 64 + ii) * 32 + d0);
    }
    __syncthreads();
    #pragma unroll 4
    for (int ii = 0; ii < 64; ++ii) {
      float4 wv = *(float4*)&Wl[ii][c0];
      int i = ic * 64 + ii;
      #pragma unroll
      for (int r = 0; r < 8; ++r) {
        float xv = xl[nb + r][i];
        acc[r][0] += xv * wv.x; acc[r][1] += xv * wv.y;
        acc[r][2] += xv * wv.z; acc[r][3] += xv * wv.w;
      }
    }
  }
  __syncthreads();
  unsigned short* tb = (unsigned short*)&xl[0][0];   // bf16 [128][66]
  float* pb = &Wl[0][0];                             // float [2][64][33]
  int hh = c0 >> 5, d0 = c0 & 31;
  float4 adv = *(const float4*)(a + hh * 64 + d0);
  float4 asv = *(const float4*)(a + hh * 64 + 32 + d0);
  #pragma unroll
  for (int cc = 0; cc < 4; ++cc) {
    unsigned int* dst = (unsigned int*)(tb + (c0 + cc) * 66 + nb);
    #pragma unroll
    for (int p = 0; p < 4; ++p)
      dst[p] = pack2bf(acc[2 * p][cc], acc[2 * p + 1][cc]);
  }
  #pragma unroll
  for (int r = 0; r < 8; ++r) {
    float pd = acc[r][0] * adv.x + acc[r][1] * adv.y + acc[r][2] * adv.z + acc[r][3] * adv.w;
    float ps = acc[r][0] * asv.x + acc[r][1] * asv.y + acc[r][2] * asv.z + acc[r][3] * asv.w;
    pb[(nb + r) * 33 + cg] = pd;
    pb[2112 + (nb + r) * 33 + cg] = ps;
  }
  __syncthreads();
  {
    int row = t >> 1, half = t & 1;
    const unsigned int* s32 = (const unsigned int*)(tb + row * 66 + half * 32);
    unsigned int v[16];
    #pragma unroll
    for (int q = 0; q < 16; ++q) v[q] = s32[q];
    unsigned short* gdst = hfT + (size_t)row * N_NODES + n0 + half * 32;
    #pragma unroll
    for (int q = 0; q < 4; ++q) {
      uint4 w4; w4.x = v[4 * q]; w4.y = v[4 * q + 1]; w4.z = v[4 * q + 2]; w4.w = v[4 * q + 3];
      *(uint4*)(gdst + q * 8) = w4;
    }
  }
  for (int task = t; task < 512; task += 256) {
    int n = task & 63, hz = task >> 6;
    int h = hz & 3, sdx = hz >> 2;
    const float* src = pb + sdx * 2112 + n * 33 + h * 8;
    float s = src[0] + src[1] + src[2] + src[3] + src[4] + src[5] + src[6] + src[7];
    float* out = sdx ? s_src2 : s_dst2;
    out[h * N_NODES + n0 + n] = s * LOG2E;
  }
}

// one m-tile k-step: weights in A-layout, 2 value-MFMAs + 1 z-MFMA (ones B)
__device__ __forceinline__ void gat_tile(float ss, uint32 bits8,
                                         const float (&dv)[8], short8 b0, short8 b1,
                                         short8 ones, f32x4& a0, f32x4& a1, f32x4& az) {
  float w[8];
  #pragma unroll
  for (int j = 0; j < 8; ++j) {
    float e = ss + dv[j];                    // (s_src+s_dst) * log2e
    float lr = fmaxf(e, 0.2f * e);           // leaky-relu (log2 domain)
    float ex = __ocml_native_exp2_f32(lr);   // v_exp_f32
    w[j] = (bits8 & (1u << j)) ? ex : 0.f;
  }
  union { uint32 u4[4]; short8 v; } afr;
  #pragma unroll
  for (int j = 0; j < 4; ++j) afr.u4[j] = pack2bf(w[2 * j], w[2 * j + 1]);
  a0 = __builtin_amdgcn_mfma_f32_16x16x32_bf16(afr.v, b0, a0, 0, 0, 0);
  a1 = __builtin_amdgcn_mfma_f32_16x16x32_bf16(afr.v, b1, a1, 0, 0, 0);
  az = __builtin_amdgcn_mfma_f32_16x16x32_bf16(afr.v, ones, az, 0, 0, 0);
}

// one k-step across the 4 m-tiles (shared d/B operands)
__device__ __forceinline__ void step4(uint32 w0, uint32 w1, uint32 w2, uint32 w3,
                                      int sh, const float* sdp, int koff,
                                      int4 B0i, int4 B1i, short8 ones,
                                      float ss0, float ss1, float ss2, float ss3,
                                      f32x4& a00, f32x4& a01, f32x4& a10, f32x4& a11,
                                      f32x4& a20, f32x4& a21, f32x4& a30, f32x4& a31,
                                      f32x4& az0, f32x4& az1, f32x4& az2, f32x4& az3) {
  f32x4 d0 = *(const f32x4*)(sdp + koff);
  f32x4 d1 = *(const f32x4*)(sdp + koff + 4);
  float dv[8] = {d0[0], d0[1], d0[2], d0[3], d1[0], d1[1], d1[2], d1[3]};
  union { int4 i; short8 v; } b0u, b1u;
  b0u.i = B0i; b1u.i = B1i;
  gat_tile(ss0, (w0 >> sh) & 0xffu, dv, b0u.v, b1u.v, ones, a00, a01, az0);
  gat_tile(ss1, (w1 >> sh) & 0xffu, dv, b0u.v, b1u.v, ones, a10, a11, az1);
  gat_tile(ss2, (w2 >> sh) & 0xffu, dv, b0u.v, b1u.v, ones, a20, a21, az2);
  gat_tile(ss3, (w3 >> sh) & 0xffu, dv, b0u.v, b1u.v, ones, a30, a31, az3);
}

// K2: fused masked-softmax aggregate. Block = 4 waves = 4 heads x 64 rows
// (4 m-tiles) x k-slice 768 (split 8). Outer loop of 4 k-steps: burst of
// 12 independent loads (4 x uint4 masks + 8 x int4 hfT frags, named scalars)
// then sched_barrier then compute — one L2 latency per ~2000 cyc of VALU.
__global__ __launch_bounds__(256, 3) void k2_attn(const uint32* __restrict__ maskw,
                                                  const unsigned short* __restrict__ hfT,
                                                  const float* __restrict__ s_src2,
                                                  const float* __restrict__ s_dst2,
                                                  float* __restrict__ Zpart,
                                                  float* __restrict__ part) {
  __shared__ float sd[4][768];   // 12 KB
  int t = threadIdx.x;
  int h = t >> 6, lane = t & 63, m = lane & 15, quad = lane >> 4;
  int sh = quad << 3;
  int bx = blockIdx.x;
  int slice = bx & 7, mg = bx >> 3;
  int i0 = mg << 6, kbase = slice * 768;
  {
    const float4* g = (const float4*)s_dst2;
    float4* l = (float4*)sd;
    int kb4 = kbase >> 2;
    #pragma unroll
    for (int r = 0; r < 3; ++r) {
      int u = t + (r << 8);
      int hx = u / 192, uu = u - hx * 192;
      l[hx * 192 + uu] = g[hx * 1536 + kb4 + uu];
    }
  }
  float ss0 = s_src2[h * N_NODES + i0 + m];
  float ss1 = s_src2[h * N_NODES + i0 + 16 + m];
  float ss2 = s_src2[h * N_NODES + i0 + 32 + m];
  float ss3 = s_src2[h * N_NODES + i0 + 48 + m];
  __syncthreads();

  const unsigned short* hp0 = hfT + (size_t)(h * 32 + m) * N_NODES + kbase + sh;
  const unsigned short* hp1 = hp0 + (size_t)16 * N_NODES;
  const uint32* mr0 = maskw + (size_t)(i0 + m) * 192 + slice * 24;
  const uint32* mr1 = mr0 + 16 * 192;
  const uint32* mr2 = mr0 + 32 * 192;
  const uint32* mr3 = mr0 + 48 * 192;
  const float* sdp = &sd[h][0] + sh;

  f32x4 a00 = {0,0,0,0}, a01 = {0,0,0,0};
  f32x4 a10 = {0,0,0,0}, a11 = {0,0,0,0};
  f32x4 a20 = {0,0,0,0}, a21 = {0,0,0,0};
  f32x4 a30 = {0,0,0,0}, a31 = {0,0,0,0};
  f32x4 az0 = {0,0,0,0}, az1 = {0,0,0,0};
  f32x4 az2 = {0,0,0,0}, az3 = {0,0,0,0};
  union { uint32 u[4]; short8 v; } ones;
  #pragma unroll
  for (int q = 0; q < 4; ++q) ones.u[q] = 0x3F803F80u;

  #pragma unroll 1
  for (int o = 0; o < 6; ++o) {
    int ko = o << 7;   // element offset of this 4-step group
    // --- load burst: 4 mask uint4 (4 steps each) + 8 hfT int4 frags
    uint4 M0 = *(const uint4*)(mr0 + (o << 2));
    uint4 M1 = *(const uint4*)(mr1 + (o << 2));
    uint4 M2 = *(const uint4*)(mr2 + (o << 2));
    uint4 M3 = *(const uint4*)(mr3 + (o << 2));
    int4 B00 = *(const int4*)(hp0 + ko),      B01 = *(const int4*)(hp1 + ko);
    int4 B10 = *(const int4*)(hp0 + ko + 32), B11 = *(const int4*)(hp1 + ko + 32);
    int4 B20 = *(const int4*)(hp0 + ko + 64), B21 = *(const int4*)(hp1 + ko + 64);
    int4 B30 = *(const int4*)(hp0 + ko + 96), B31 = *(const int4*)(hp1 + ko + 96);
    __builtin_amdgcn_sched_barrier(0);
    // --- 4 k-steps of compute
    step4(M0.x, M1.x, M2.x, M3.x, sh, sdp, ko,      B00, B01, ones.v,
          ss0, ss1, ss2, ss3, a00, a01, a10, a11, a20, a21, a30, a31,
          az0, az1, az2, az3);
    step4(M0.y, M1.y, M2.y, M3.y, sh, sdp, ko + 32, B10, B11, ones.v,
          ss0, ss1, ss2, ss3, a00, a01, a10, a11, a20, a21, a30, a31,
          az0, az1, az2, az3);
    step4(M0.z, M1.z, M2.z, M3.z, sh, sdp, ko + 64, B20, B21, ones.v,
          ss0, ss1, ss2, ss3, a00, a01, a10, a11, a20, a21, a30, a31,
          az0, az1, az2, az3);
    step4(M0.w, M1.w, M2.w, M3.w, sh, sdp, ko + 96, B30, B31, ones.v,
          ss0, ss1, ss2, ss3, a00, a01, a10, a11, a20, a21, a30, a31,
          az0, az1, az2, az3);
  }

  // Z: ones-MFMA made every column hold the row sum; lanes m==0 write
  if (m == 0) {
    float* zb = Zpart + h * N_NODES + i0 + (quad << 2);
    #pragma unroll
    for (int r = 0; r < 4; ++r) {
      atomicAdd(zb + r, az0[r]);
      atomicAdd(zb + 16 + r, az1[r]);
      atomicAdd(zb + 32 + r, az2[r]);
      atomicAdd(zb + 48 + r, az3[r]);
    }
  }
  // partials: (h, row, col) flat; D layout: col=lane&15, row=quad*4+reg
  float* pb = part + (size_t)h * (N_NODES * 32) + (size_t)i0 * 32;
  #pragma unroll
  for (int r = 0; r < 4; ++r) {
    int row = (quad << 2) + r;
    atomicAdd(&pb[row * 32 + m], a00[r]);
    atomicAdd(&pb[row * 32 + 16 + m], a01[r]);
    atomicAdd(&pb[(16 + row) * 32 + m], a10[r]);
    atomicAdd(&pb[(16 + row) * 32 + 16 + m], a11[r]);
    atomicAdd(&pb[(32 + row) * 32 + m], a20[r]);
    atomicAdd(&pb[(32 + row) * 32 + 16 + m], a21[r]);
    atomicAdd(&pb[(48 + row) * 32 + m], a30[r]);
    atomicAdd(&pb[(48 + row) * 32 + 16 + m], a31[r]);
  }
}

// K3: out = part / Z
__global__ __launch_bounds__(256) void k3_final(const float* __restrict__ part,
                                                const float* __restrict__ Zpart,
                                                float* __restrict__ out) {
  unsigned int idx4 = blockIdx.x * 256 + threadIdx.x;   // float4 index
  unsigned int h = idx4 / 49152u;
  unsigned int i = (idx4 - h * 49152u) >> 3;
  float rz = 1.0f / Zpart[h * N_NODES + i];
  f32x4 p = ((const f32x4*)part)[idx4];
  ((f32x4*)out)[idx4] = p * rz;
}

extern "C" void kernel_launch(void* const* d_in, const int* in_sizes, int n_in,
                              void* d_out, int out_size, void* d_ws, size_t ws_size,
                              hipStream_t stream) {
  const float* x = (const float*)d_in[0];
  const int* adj = (const int*)d_in[1];
  const float* W = (const float*)d_in[2];
  const float* a = (const float*)d_in[3];
  float* out = (float*)d_out;

  float* wsf = (float*)d_ws;
  unsigned short* hfT = (unsigned short*)wsf;       // 128*6144 bf16 (1.5 MB)
  float* s_src2 = wsf + 393216;                     // 4*6144
  float* s_dst2 = s_src2 + 24576;                   // 4*6144
  float* part   = s_dst2 + 24576;                   // 786432 (3 MB)
  float* Zpart  = part + 786432;                    // 4*6144
  uint64* mask64 = (uint64*)(Zpart + 24576);        // 6144*96 u64 (4.7 MB)

  (void)hipMemsetAsync(part, 0, (786432 + 24576) * sizeof(float), stream);
  hipLaunchKernelGGL(k0_pack, dim3(1536), dim3(256), 0, stream, adj, mask64);
  hipLaunchKernelGGL(k1_feat, dim3(96), dim3(256), 0, stream, x, W, a, hfT, s_src2, s_dst2);
  hipLaunchKernelGGL(k2_attn, dim3(768), dim3(256), 0, stream,
                     (const uint32*)mask64, hfT, s_src2, s_dst2, Zpart, part);
  hipLaunchKernelGGL(k3_final, dim3(768), dim3(256), 0, stream, part, Zpart, out);
}

// Round 11
// 308.507 us; speedup vs baseline: 1.0299x; 1.0299x over previous
//
#include <hip/hip_runtime.h>
#include <stdint.h>

#define N_NODES 6144
#define LOG2E 1.44269504088896f

typedef float f32x4 __attribute__((ext_vector_type(4)));
typedef short short8 __attribute__((ext_vector_type(8)));
typedef unsigned int uint32;
typedef unsigned long long uint64;

extern "C" __device__ float __ocml_native_exp2_f32(float);

// pack two floats -> two bf16 (round-half-up) in one u32: lo=a, hi=b
__device__ __forceinline__ unsigned int pack2bf(float a, float b) {
  unsigned int ua = __float_as_uint(a) + 0x8000u;
  unsigned int ub = __float_as_uint(b) + 0x8000u;
  return __builtin_amdgcn_perm(ub, ua, 0x07060302u);
}

// K0: bit-pack adjacency via wave ballot. Lane reads ONE int (coalesced
// 256B per wave instr), ballot packs 64 edges, one lane stores the u64.
__global__ __launch_bounds__(256) void k0_pack(const int* __restrict__ adj,
                                               uint64* __restrict__ mask64) {
  int t = threadIdx.x;
  int wid = t >> 6, lane = t & 63;
  int row = blockIdx.x * 4 + wid;
  const int* ar = adj + (size_t)row * N_NODES + lane;
  uint64* mr = mask64 + (size_t)row * 96;
  #pragma unroll 8
  for (int c = 0; c < 96; ++c) {
    int v = ar[c << 6];
    uint64 b = __ballot(v != 0);
    if (lane == (c & 63)) mr[c] = b;
  }
}

// K1: h = x*W (fp32). hfT (bf16 [c][n]) coalesced via LDS transpose;
// s_src2/s_dst2 = (h . a_{src,dst}) * log2(e).
__global__ __launch_bounds__(256) void k1_feat(const float* __restrict__ x,
                                               const float* __restrict__ W,
                                               const float* __restrict__ a,
                                               unsigned short* __restrict__ hfT,
                                               float* __restrict__ s_src2,
                                               float* __restrict__ s_dst2) {
  __shared__ float xl[64][132];
  __shared__ float Wl[64][128];
  int t = threadIdx.x;
  int n0 = blockIdx.x * 64;
  for (int u = t; u < 2048; u += 256) {
    int row = u >> 5, c4 = (u & 31) << 2;
    *(float4*)&xl[row][c4] = *(const float4*)(x + (size_t)(n0 + row) * 128 + c4);
  }
  int cg = t & 31, c0 = cg << 2;
  int ng = t >> 5, nb = ng << 3;
  float acc[8][4] = {};
  for (int ic = 0; ic < 2; ++ic) {
    __syncthreads();
    for (int u = t; u < 2048; u += 256) {
      int ii = u >> 5, c4 = (u & 31) << 2;
      int hh = c4 >> 5, d0 = c4 & 31;
      *(float4*)&Wl[ii][c4] = *(const float4*)(W + hh * 4096 + (ic * 64 + ii) * 32 + d0);
    }
    __syncthreads();
    #pragma unroll 4
    for (int ii = 0; ii < 64; ++ii) {
      float4 wv = *(float4*)&Wl[ii][c0];
      int i = ic * 64 + ii;
      #pragma unroll
      for (int r = 0; r < 8; ++r) {
        float xv = xl[nb + r][i];
        acc[r][0] += xv * wv.x; acc[r][1] += xv * wv.y;
        acc[r][2] += xv * wv.z; acc[r][3] += xv * wv.w;
      }
    }
  }
  __syncthreads();
  unsigned short* tb = (unsigned short*)&xl[0][0];   // bf16 [128][66]
  float* pb = &Wl[0][0];                             // float [2][64][33]
  int hh = c0 >> 5, d0 = c0 & 31;
  float4 adv = *(const float4*)(a + hh * 64 + d0);
  float4 asv = *(const float4*)(a + hh * 64 + 32 + d0);
  #pragma unroll
  for (int cc = 0; cc < 4; ++cc) {
    unsigned int* dst = (unsigned int*)(tb + (c0 + cc) * 66 + nb);
    #pragma unroll
    for (int p = 0; p < 4; ++p)
      dst[p] = pack2bf(acc[2 * p][cc], acc[2 * p + 1][cc]);
  }
  #pragma unroll
  for (int r = 0; r < 8; ++r) {
    float pd = acc[r][0] * adv.x + acc[r][1] * adv.y + acc[r][2] * adv.z + acc[r][3] * adv.w;
    float ps = acc[r][0] * asv.x + acc[r][1] * asv.y + acc[r][2] * asv.z + acc[r][3] * asv.w;
    pb[(nb + r) * 33 + cg] = pd;
    pb[2112 + (nb + r) * 33 + cg] = ps;
  }
  __syncthreads();
  {
    int row = t >> 1, half = t & 1;
    const unsigned int* s32 = (const unsigned int*)(tb + row * 66 + half * 32);
    unsigned int v[16];
    #pragma unroll
    for (int q = 0; q < 16; ++q) v[q] = s32[q];
    unsigned short* gdst = hfT + (size_t)row * N_NODES + n0 + half * 32;
    #pragma unroll
    for (int q = 0; q < 4; ++q) {
      uint4 w4; w4.x = v[4 * q]; w4.y = v[4 * q + 1]; w4.z = v[4 * q + 2]; w4.w = v[4 * q + 3];
      *(uint4*)(gdst + q * 8) = w4;
    }
  }
  for (int task = t; task < 512; task += 256) {
    int n = task & 63, hz = task >> 6;
    int h = hz & 3, sdx = hz >> 2;
    const float* src = pb + sdx * 2112 + n * 33 + h * 8;
    float s = src[0] + src[1] + src[2] + src[3] + src[4] + src[5] + src[6] + src[7];
    float* out = sdx ? s_src2 : s_dst2;
    out[h * N_NODES + n0 + n] = s * LOG2E;
  }
}

// one m-tile k-step: weights in A-layout, 2 value-MFMAs + 1 z-MFMA (ones B)
__device__ __forceinline__ void gat_tile(float ss, uint32 bits8,
                                         const float (&dv)[8], short8 b0, short8 b1,
                                         short8 ones, f32x4& a0, f32x4& a1, f32x4& az) {
  float w[8];
  #pragma unroll
  for (int j = 0; j < 8; ++j) {
    float e = ss + dv[j];                    // (s_src+s_dst) * log2e
    float lr = fmaxf(e, 0.2f * e);           // leaky-relu (log2 domain)
    float ex = __ocml_native_exp2_f32(lr);   // v_exp_f32
    w[j] = (bits8 & (1u << j)) ? ex : 0.f;
  }
  union { uint32 u4[4]; short8 v; } afr;
  #pragma unroll
  for (int j = 0; j < 4; ++j) afr.u4[j] = pack2bf(w[2 * j], w[2 * j + 1]);
  a0 = __builtin_amdgcn_mfma_f32_16x16x32_bf16(afr.v, b0, a0, 0, 0, 0);
  a1 = __builtin_amdgcn_mfma_f32_16x16x32_bf16(afr.v, b1, a1, 0, 0, 0);
  az = __builtin_amdgcn_mfma_f32_16x16x32_bf16(afr.v, ones, az, 0, 0, 0);
}

// one k-step across the 4 m-tiles (shared d/B operands)
__device__ __forceinline__ void step4(uint32 w0, uint32 w1, uint32 w2, uint32 w3,
                                      int sh, const float* sdp, int koff,
                                      int4 B0i, int4 B1i, short8 ones,
                                      float ss0, float ss1, float ss2, float ss3,
                                      f32x4& a00, f32x4& a01, f32x4& a10, f32x4& a11,
                                      f32x4& a20, f32x4& a21, f32x4& a30, f32x4& a31,
                                      f32x4& az0, f32x4& az1, f32x4& az2, f32x4& az3) {
  f32x4 d0 = *(const f32x4*)(sdp + koff);
  f32x4 d1 = *(const f32x4*)(sdp + koff + 4);
  float dv[8] = {d0[0], d0[1], d0[2], d0[3], d1[0], d1[1], d1[2], d1[3]};
  union { int4 i; short8 v; } b0u, b1u;
  b0u.i = B0i; b1u.i = B1i;
  gat_tile(ss0, (w0 >> sh) & 0xffu, dv, b0u.v, b1u.v, ones, a00, a01, az0);
  gat_tile(ss1, (w1 >> sh) & 0xffu, dv, b0u.v, b1u.v, ones, a10, a11, az1);
  gat_tile(ss2, (w2 >> sh) & 0xffu, dv, b0u.v, b1u.v, ones, a20, a21, az2);
  gat_tile(ss3, (w3 >> sh) & 0xffu, dv, b0u.v, b1u.v, ones, a30, a31, az3);
}

// K2: fused masked-softmax aggregate. Block = 4 waves = 4 heads x 64 rows
// (4 m-tiles) x k-slice 768 (split 8). Outer loop of 4 k-steps: burst of
// 12 independent loads then compute. Epilogue: plain per-slice stores
// (no atomics) — part[slice][h][i][d], Zpart[slice][h][i].
__global__ __launch_bounds__(256, 3) void k2_attn(const uint32* __restrict__ maskw,
                                                  const unsigned short* __restrict__ hfT,
                                                  const float* __restrict__ s_src2,
                                                  const float* __restrict__ s_dst2,
                                                  float* __restrict__ Zpart,
                                                  float* __restrict__ part) {
  __shared__ float sd[4][768];   // 12 KB
  int t = threadIdx.x;
  int h = t >> 6, lane = t & 63, m = lane & 15, quad = lane >> 4;
  int sh = quad << 3;
  int bx = blockIdx.x;
  int slice = bx & 7, mg = bx >> 3;
  int i0 = mg << 6, kbase = slice * 768;
  {
    const float4* g = (const float4*)s_dst2;
    float4* l = (float4*)sd;
    int kb4 = kbase >> 2;
    #pragma unroll
    for (int r = 0; r < 3; ++r) {
      int u = t + (r << 8);
      int hx = u / 192, uu = u - hx * 192;
      l[hx * 192 + uu] = g[hx * 1536 + kb4 + uu];
    }
  }
  float ss0 = s_src2[h * N_NODES + i0 + m];
  float ss1 = s_src2[h * N_NODES + i0 + 16 + m];
  float ss2 = s_src2[h * N_NODES + i0 + 32 + m];
  float ss3 = s_src2[h * N_NODES + i0 + 48 + m];
  __syncthreads();

  const unsigned short* hp0 = hfT + (size_t)(h * 32 + m) * N_NODES + kbase + sh;
  const unsigned short* hp1 = hp0 + (size_t)16 * N_NODES;
  const uint32* mr0 = maskw + (size_t)(i0 + m) * 192 + slice * 24;
  const uint32* mr1 = mr0 + 16 * 192;
  const uint32* mr2 = mr0 + 32 * 192;
  const uint32* mr3 = mr0 + 48 * 192;
  const float* sdp = &sd[h][0] + sh;

  f32x4 a00 = {0,0,0,0}, a01 = {0,0,0,0};
  f32x4 a10 = {0,0,0,0}, a11 = {0,0,0,0};
  f32x4 a20 = {0,0,0,0}, a21 = {0,0,0,0};
  f32x4 a30 = {0,0,0,0}, a31 = {0,0,0,0};
  f32x4 az0 = {0,0,0,0}, az1 = {0,0,0,0};
  f32x4 az2 = {0,0,0,0}, az3 = {0,0,0,0};
  union { uint32 u[4]; short8 v; } ones;
  #pragma unroll
  for (int q = 0; q < 4; ++q) ones.u[q] = 0x3F803F80u;

  #pragma unroll 1
  for (int o = 0; o < 6; ++o) {
    int ko = o << 7;   // element offset of this 4-step group
    // --- load burst: 4 mask uint4 (4 steps each) + 8 hfT int4 frags
    uint4 M0 = *(const uint4*)(mr0 + (o << 2));
    uint4 M1 = *(const uint4*)(mr1 + (o << 2));
    uint4 M2 = *(const uint4*)(mr2 + (o << 2));
    uint4 M3 = *(const uint4*)(mr3 + (o << 2));
    int4 B00 = *(const int4*)(hp0 + ko),      B01 = *(const int4*)(hp1 + ko);
    int4 B10 = *(const int4*)(hp0 + ko + 32), B11 = *(const int4*)(hp1 + ko + 32);
    int4 B20 = *(const int4*)(hp0 + ko + 64), B21 = *(const int4*)(hp1 + ko + 64);
    int4 B30 = *(const int4*)(hp0 + ko + 96), B31 = *(const int4*)(hp1 + ko + 96);
    __builtin_amdgcn_sched_barrier(0);
    // --- 4 k-steps of compute
    step4(M0.x, M1.x, M2.x, M3.x, sh, sdp, ko,      B00, B01, ones.v,
          ss0, ss1, ss2, ss3, a00, a01, a10, a11, a20, a21, a30, a31,
          az0, az1, az2, az3);
    step4(M0.y, M1.y, M2.y, M3.y, sh, sdp, ko + 32, B10, B11, ones.v,
          ss0, ss1, ss2, ss3, a00, a01, a10, a11, a20, a21, a30, a31,
          az0, az1, az2, az3);
    step4(M0.z, M1.z, M2.z, M3.z, sh, sdp, ko + 64, B20, B21, ones.v,
          ss0, ss1, ss2, ss3, a00, a01, a10, a11, a20, a21, a30, a31,
          az0, az1, az2, az3);
    step4(M0.w, M1.w, M2.w, M3.w, sh, sdp, ko + 96, B30, B31, ones.v,
          ss0, ss1, ss2, ss3, a00, a01, a10, a11, a20, a21, a30, a31,
          az0, az1, az2, az3);
  }

  // Z per-slice stores: ones-MFMA made every column hold the row sum
  if (m == 0) {
    float* zb = Zpart + (size_t)slice * 24576 + h * N_NODES + i0 + (quad << 2);
    #pragma unroll
    for (int r = 0; r < 4; ++r) {
      zb[r] = az0[r];
      zb[16 + r] = az1[r];
      zb[32 + r] = az2[r];
      zb[48 + r] = az3[r];
    }
  }
  // partial stores: part[slice][h][row][col]; D: col=lane&15, row=quad*4+reg
  float* pb = part + (size_t)slice * 786432 + (size_t)h * (N_NODES * 32) +
              (size_t)i0 * 32;
  #pragma unroll
  for (int r = 0; r < 4; ++r) {
    int row = (quad << 2) + r;
    pb[row * 32 + m] = a00[r];
    pb[row * 32 + 16 + m] = a01[r];
    pb[(16 + row) * 32 + m] = a10[r];
    pb[(16 + row) * 32 + 16 + m] = a11[r];
    pb[(32 + row) * 32 + m] = a20[r];
    pb[(32 + row) * 32 + 16 + m] = a21[r];
    pb[(48 + row) * 32 + m] = a30[r];
    pb[(48 + row) * 32 + 16 + m] = a31[r];
  }
}

// K3: out = sum_s part[s] / sum_s Z[s]
__global__ __launch_bounds__(256) void k3_final(const float* __restrict__ part,
                                                const float* __restrict__ Zpart,
                                                float* __restrict__ out) {
  unsigned int idx4 = blockIdx.x * 256 + threadIdx.x;   // float4 index
  unsigned int h = idx4 / 49152u;
  unsigned int i = (idx4 - h * 49152u) >> 3;
  float z = 0.f;
  #pragma unroll
  for (int s = 0; s < 8; ++s) z += Zpart[s * 24576u + h * N_NODES + i];
  f32x4 p = {0.f, 0.f, 0.f, 0.f};
  const f32x4* P = (const f32x4*)part;
  #pragma unroll
  for (int s = 0; s < 8; ++s) p += P[(size_t)s * 196608u + idx4];
  float rz = 1.0f / z;
  ((f32x4*)out)[idx4] = p * rz;
}

extern "C" void kernel_launch(void* const* d_in, const int* in_sizes, int n_in,
                              void* d_out, int out_size, void* d_ws, size_t ws_size,
                              hipStream_t stream) {
  const float* x = (const float*)d_in[0];
  const int* adj = (const int*)d_in[1];
  const float* W = (const float*)d_in[2];
  const float* a = (const float*)d_in[3];
  float* out = (float*)d_out;

  float* wsf = (float*)d_ws;
  unsigned short* hfT = (unsigned short*)wsf;       // 128*6144 bf16 (1.5 MB)
  float* s_src2 = wsf + 393216;                     // 4*6144
  float* s_dst2 = s_src2 + 24576;                   // 4*6144
  float* part   = s_dst2 + 24576;                   // 8 slices * 786432 (24 MB)
  float* Zpart  = part + 8 * 786432;                // 8 slices * 24576
  uint64* mask64 = (uint64*)(Zpart + 8 * 24576);    // 6144*96 u64 (4.7 MB)

  hipLaunchKernelGGL(k0_pack, dim3(1536), dim3(256), 0, stream, adj, mask64);
  hipLaunchKernelGGL(k1_feat, dim3(96), dim3(256), 0, stream, x, W, a, hfT, s_src2, s_dst2);
  hipLaunchKernelGGL(k2_attn, dim3(768), dim3(256), 0, stream,
                     (const uint32*)mask64, hfT, s_src2, s_dst2, Zpart, part);
  hipLaunchKernelGGL(k3_final, dim3(768), dim3(256), 0, stream, part, Zpart, out);
}